// Round 2
// baseline (538.560 us; speedup 1.0000x reference)
//
#include <hip/hip_runtime.h>

// SimpleLSTM: 2-layer LSTM (B=512,T=256,F=64,U=128) + Dense(1,relu).
// Persistent-RNN: fp16 weights in VGPRs (launch_bounds(512,2) -> 256-reg budget),
// 256 WGs x 512 thr, 2 batch rows/WG. Two-phase step:
//   A: MFMA (zero-page compact A-frags) -> z fp32 to LDS -> barrier
//   B: 128 threads gate-math (persistent c regs), packed h2 writes -> barrier
// log2e folded into weights/bias => sigmoid/tanh are exp2+rcp only.

#define T_STEPS 256
#define BATCH   512
#define NU      128
#define FDIM    64

typedef _Float16 h8 __attribute__((ext_vector_type(8)));
typedef _Float16 h4 __attribute__((ext_vector_type(4)));
typedef _Float16 h2 __attribute__((ext_vector_type(2)));
typedef float    f4 __attribute__((ext_vector_type(4)));
typedef float    f2 __attribute__((ext_vector_type(2)));

#define LOG2E    1.4426950408889634f
#define TWOLOG2E 2.8853900817779268f

#if __has_builtin(__builtin_amdgcn_exp2f)
#define EXP2F(x) __builtin_amdgcn_exp2f(x)
#else
#define EXP2F(x) exp2f(x)
#endif
#if __has_builtin(__builtin_amdgcn_rcpf)
#define RCPF(x) __builtin_amdgcn_rcpf(x)
#else
#define RCPF(x) (1.0f / (x))
#endif

__device__ __forceinline__ float sigm2(float s) {   // s = z*log2e
    return RCPF(1.0f + EXP2F(-s));
}
__device__ __forceinline__ float tanh2(float t) {   // t = 2*z*log2e
    return 1.0f - 2.0f * RCPF(1.0f + EXP2F(t));
}

// ---- weight prep: transpose to col-major [col][k], cast fp16, fold log2e ----
__global__ void prep_weights(const float* __restrict__ W1, const float* __restrict__ U1,
                             const float* __restrict__ b1, const float* __restrict__ W2,
                             const float* __restrict__ U2, const float* __restrict__ b2,
                             _Float16* __restrict__ Wp1, _Float16* __restrict__ Up1,
                             _Float16* __restrict__ Wp2, _Float16* __restrict__ Up2,
                             float* __restrict__ bp1, float* __restrict__ bp2) {
    int i = blockIdx.x * 256 + threadIdx.x;
    if (i < 32768) {                       // Wp1 [512][64] from W1 [64][512]
        int col = i >> 6, k = i & 63;
        float sc = ((col >> 7) == 2) ? TWOLOG2E : LOG2E;
        Wp1[i] = (_Float16)(W1[k * 512 + col] * sc);
    } else if (i < 32768 + 65536) {        // Up1 [512][128] from U1 [128][512]
        int j = i - 32768; int col = j >> 7, k = j & 127;
        float sc = ((col >> 7) == 2) ? TWOLOG2E : LOG2E;
        Up1[j] = (_Float16)(U1[k * 512 + col] * sc);
    } else if (i < 32768 + 131072) {       // Wp2 [512][128] from W2 [128][512]
        int j = i - 98304; int col = j >> 7, k = j & 127;
        float sc = ((col >> 7) == 2) ? TWOLOG2E : LOG2E;
        Wp2[j] = (_Float16)(W2[k * 512 + col] * sc);
    } else if (i < 32768 + 196608) {       // Up2 [512][128] from U2 [128][512]
        int j = i - 163840; int col = j >> 7, k = j & 127;
        float sc = ((col >> 7) == 2) ? TWOLOG2E : LOG2E;
        Up2[j] = (_Float16)(U2[k * 512 + col] * sc);
    } else if (i < 32768 + 196608 + 1024) {
        int j = i - 229376;
        if (j < 512) {
            float sc = ((j >> 7) == 2) ? TWOLOG2E : LOG2E;
            bp1[j] = b1[j] * sc;
        } else {
            int col = j - 512;
            float sc = ((col >> 7) == 2) ? TWOLOG2E : LOG2E;
            bp2[col] = b2[col] * sc;
        }
    }
}

// ---- LSTM layer kernel ----
// IS_A: input = x (f32 [B,T,F]), writes hs fp16 [T,B,U].
// !IS_A: input = hs (fp16 [T,B,U]), fused dense at end.
template <bool IS_A>
__global__ __launch_bounds__(512, 2) void lstm_layer(
    const float* __restrict__ xA, const _Float16* __restrict__ xB,
    const _Float16* __restrict__ Wp,   // [512][KX] col-major, scaled fp16
    const _Float16* __restrict__ Up,   // [512][128]
    const float* __restrict__ bp,      // [512] scaled
    _Float16* __restrict__ hs_out,
    const float* __restrict__ Wd, const float* __restrict__ bd,
    float* __restrict__ dout) {
    constexpr int KX  = IS_A ? 64 : 128;
    constexpr int KXS = KX / 32;
    constexpr int PX  = IS_A ? 72 : 136;  // halfs; rows 16B-aligned
    constexpr int PH  = 136;
    constexpr int ZP  = 0;                // zero page (16 halfs)
    constexpr int HO  = 16;               // h buffer: 2 rows x PH
    constexpr int X0  = HO + 2 * PH;      // x buffer parity 0: 2 rows x PX
    constexpr int X1  = X0 + 2 * PX;      // x buffer parity 1
    constexpr int ZO  = X1 + 2 * PX;      // z buffer: 2*512 fp32 (as halfs: 2048)
    constexpr int SMH = ZO + 2048;

    __shared__ __align__(16) _Float16 sm[SMH];

    const int tid  = threadIdx.x;
    const int lane = tid & 63;
    const int wv   = tid >> 6;       // 0..7, each owns 16 units x 4 gates
    const int m    = lane & 15;
    const int kc   = lane >> 4;      // quad 0..3
    const int u0   = wv * 16;
    const int b0   = blockIdx.x * 2;

    // zero LDS (zero page + h0 = 0)
    for (int i = tid; i < SMH; i += 512) sm[i] = (_Float16)0.0f;

    // weight fragments -> registers (B-frag: B[k=kc*8+j][n=m], col-major source)
    h8 wf[4][KXS], uf[4][4];
#pragma unroll
    for (int g = 0; g < 4; g++) {
#pragma unroll
        for (int ks = 0; ks < KXS; ks++)
            wf[g][ks] = *(const h8*)&Wp[(g * 128 + u0 + m) * KX + ks * 32 + kc * 8];
#pragma unroll
        for (int ks = 0; ks < 4; ks++)
            uf[g][ks] = *(const h8*)&Up[(g * 128 + u0 + m) * 128 + ks * 32 + kc * 8];
    }

    // phase-B identity: thread tid<128 owns (row=tid>>6, units uu,uu+1)
    const int row = tid >> 6;
    const int uu  = (tid & 63) * 2;
    float cst[2] = {0.0f, 0.0f};
    float bia[4][2];
    if (tid < 128) {
#pragma unroll
        for (int g = 0; g < 4; g++) {
            bia[g][0] = bp[g * 128 + uu];
            bia[g][1] = bp[g * 128 + uu + 1];
        }
    }

    // A-frag addresses (half-index); m>=2 lanes -> zero page (broadcast read)
    int ah[4];
#pragma unroll
    for (int ks = 0; ks < 4; ks++)
        ah[ks] = (m < 2) ? (HO + m * PH + ks * 32 + kc * 8) : ZP;
    int axs[KXS];
#pragma unroll
    for (int ks = 0; ks < KXS; ks++)
        axs[ks] = (m < 2) ? (X0 + m * PX + ks * 32 + kc * 8) : ZP;

    const int prow = lane >> 4;   // staging: lanes 0..31 of wave 4
    const int pcol = lane & 15;

    __syncthreads();   // LDS zeroed

    // stage t=0 input into x parity 0
    if (wv == 4 && lane < 32) {
        if constexpr (IS_A) {
            f4 v = *(const f4*)&xA[(size_t)((b0 + prow) * T_STEPS + 0) * FDIM + pcol * 4];
            h4 hv = {(_Float16)v.x, (_Float16)v.y, (_Float16)v.z, (_Float16)v.w};
            *(h4*)&sm[X0 + prow * PX + pcol * 4] = hv;
        } else {
            *(h8*)&sm[X0 + prow * PX + pcol * 8] =
                *(const h8*)&xB[(size_t)(0 * BATCH + b0 + prow) * NU + pcol * 8];
        }
    }
    __syncthreads();

    for (int t = 0; t < T_STEPS; t++) {
        const int p = t & 1;

        // ---- phase A ----
        // issue next-step global prefetch early (consumed in phase B)
        f4 xr; h8 xr8;
        const bool pf = (wv == 4) && (lane < 32) && (t + 1 < T_STEPS);
        if (pf) {
            if constexpr (IS_A)
                xr = *(const f4*)&xA[(size_t)((b0 + prow) * T_STEPS + (t + 1)) * FDIM + pcol * 4];
            else
                xr8 = *(const h8*)&xB[(size_t)((t + 1) * BATCH + b0 + prow) * NU + pcol * 8];
        }

        const int pxoff = (m < 2) ? (p * 2 * PX) : 0;
        h8 xa[KXS], ha[4];
#pragma unroll
        for (int ks = 0; ks < KXS; ks++)
            xa[ks] = *(const h8*)&sm[axs[ks] + pxoff];
#pragma unroll
        for (int ks = 0; ks < 4; ks++)
            ha[ks] = *(const h8*)&sm[ah[ks]];

        f4 acc[4];
#pragma unroll
        for (int g = 0; g < 4; g++) acc[g] = (f4){0.f, 0.f, 0.f, 0.f};
#pragma unroll
        for (int ks = 0; ks < KXS; ks++)
#pragma unroll
            for (int g = 0; g < 4; g++)
                acc[g] = __builtin_amdgcn_mfma_f32_16x16x32_f16(xa[ks], wf[g][ks], acc[g], 0, 0, 0);
#pragma unroll
        for (int ks = 0; ks < 4; ks++)
#pragma unroll
            for (int g = 0; g < 4; g++)
                acc[g] = __builtin_amdgcn_mfma_f32_16x16x32_f16(ha[ks], uf[g][ks], acc[g], 0, 0, 0);

        if (lane < 16) {   // rows 0,1 live in regs 0,1 of lanes 0..15
            float* zb = (float*)&sm[ZO];
#pragma unroll
            for (int g = 0; g < 4; g++) {
                zb[      g * 128 + u0 + m] = acc[g][0];
                zb[512 + g * 128 + u0 + m] = acc[g][1];
            }
        }
        __syncthreads();

        // ---- phase B ----
        if (tid < 128) {
            const float* zb = (const float*)&sm[ZO];
            f2 zi = *(const f2*)&zb[row * 512 +       uu];
            f2 zf = *(const f2*)&zb[row * 512 + 128 + uu];
            f2 zg = *(const f2*)&zb[row * 512 + 256 + uu];
            f2 zo = *(const f2*)&zb[row * 512 + 384 + uu];
            float hv[2];
#pragma unroll
            for (int j = 0; j < 2; j++) {
                float gi = sigm2(zi[j] + bia[0][j]);
                float gf = sigm2(zf[j] + bia[1][j]);
                float gg = tanh2(zg[j] + bia[2][j]);
                float go = sigm2(zo[j] + bia[3][j]);
                cst[j] = gf * cst[j] + gi * gg;
                hv[j] = go * tanh2(cst[j] * TWOLOG2E);
            }
            h2 pk = {(_Float16)hv[0], (_Float16)hv[1]};
            *(h2*)&sm[HO + row * PH + uu] = pk;
            if constexpr (IS_A)
                *(h2*)&hs_out[((size_t)t * BATCH + b0 + row) * NU + uu] = pk;
        } else if (pf) {
            const int xn = (p ? X0 : X1);
            if constexpr (IS_A) {
                h4 hv4 = {(_Float16)xr.x, (_Float16)xr.y, (_Float16)xr.z, (_Float16)xr.w};
                *(h4*)&sm[xn + prow * PX + pcol * 4] = hv4;
            } else {
                *(h8*)&sm[xn + prow * PX + pcol * 8] = xr8;
            }
        }
        __syncthreads();
    }

    if constexpr (!IS_A) {
        // h(T) sits in the compact h buffer
        if (wv == 0) {
            int rw = lane >> 5, u = lane & 31;
            float s = 0.0f;
#pragma unroll
            for (int j = 0; j < 4; j++) {
                int uum = u + j * 32;
                s += (float)sm[HO + rw * PH + uum] * Wd[uum];
            }
            s += __shfl_xor(s, 16);
            s += __shfl_xor(s, 8);
            s += __shfl_xor(s, 4);
            s += __shfl_xor(s, 2);
            s += __shfl_xor(s, 1);
            if ((lane & 31) == 0) dout[b0 + rw] = fmaxf(s + bd[0], 0.0f);
        }
    }
}

extern "C" void kernel_launch(void* const* d_in, const int* in_sizes, int n_in,
                              void* d_out, int out_size, void* d_ws, size_t ws_size,
                              hipStream_t stream) {
    const float* x  = (const float*)d_in[0];
    const float* W1 = (const float*)d_in[1];
    const float* U1 = (const float*)d_in[2];
    const float* b1 = (const float*)d_in[3];
    const float* W2 = (const float*)d_in[4];
    const float* U2 = (const float*)d_in[5];
    const float* b2 = (const float*)d_in[6];
    const float* Wd = (const float*)d_in[7];
    const float* bd = (const float*)d_in[8];
    float* out = (float*)d_out;

    const size_t HS   = 33554432;              // hs fp16 [256][512][128]
    const size_t oWp1 = HS;
    const size_t oUp1 = oWp1 + 65536;
    const size_t oWp2 = oUp1 + 131072;
    const size_t oUp2 = oWp2 + 131072;
    const size_t oBp1 = oUp2 + 131072;
    const size_t oBp2 = oBp1 + 2048;
    const size_t need = oBp2 + 2048;           // 34,017,280
    if (ws_size < need) return;

    char* ws = (char*)d_ws;
    _Float16* hs  = (_Float16*)ws;
    _Float16* Wp1 = (_Float16*)(ws + oWp1);
    _Float16* Up1 = (_Float16*)(ws + oUp1);
    _Float16* Wp2 = (_Float16*)(ws + oWp2);
    _Float16* Up2 = (_Float16*)(ws + oUp2);
    float*    bp1 = (float*)(ws + oBp1);
    float*    bp2 = (float*)(ws + oBp2);

    prep_weights<<<900, 256, 0, stream>>>(W1, U1, b1, W2, U2, b2,
                                          Wp1, Up1, Wp2, Up2, bp1, bp2);
    lstm_layer<true><<<256, 512, 0, stream>>>(x, nullptr, Wp1, Up1, bp1,
                                              hs, nullptr, nullptr, nullptr);
    lstm_layer<false><<<256, 512, 0, stream>>>(nullptr, hs, Wp2, Up2, bp2,
                                               nullptr, Wd, bd, out);
}

// Round 3
// 467.209 us; speedup vs baseline: 1.1527x; 1.1527x over previous
//
#include <hip/hip_runtime.h>

// SimpleLSTM: 2-layer LSTM (B=512,T=256,F=64,U=128) + Dense(1,relu).
// Persistent-RNN: fp16 weights pinned in VGPRs (asm pin + launch_bounds(512,2)),
// 256 WGs x 512 thr, 2 batch rows/WG, single barrier/step.
// A-frag LDS loads exec-masked to the 2 real rows (rows 2..15 are garbage,
// discarded by the C/D layout). log2e folded into weights/bias.

#define T_STEPS 256
#define BATCH   512
#define NU      128
#define FDIM    64

typedef _Float16 h8 __attribute__((ext_vector_type(8)));
typedef _Float16 h4 __attribute__((ext_vector_type(4)));
typedef float    f4 __attribute__((ext_vector_type(4)));

#define LOG2E    1.4426950408889634f
#define TWOLOG2E 2.8853900817779268f

#if __has_builtin(__builtin_amdgcn_exp2f)
#define EXP2F(x) __builtin_amdgcn_exp2f(x)
#else
#define EXP2F(x) exp2f(x)
#endif
#if __has_builtin(__builtin_amdgcn_rcpf)
#define RCPF(x) __builtin_amdgcn_rcpf(x)
#else
#define RCPF(x) (1.0f / (x))
#endif

__device__ __forceinline__ float sigm2(float s) {   // s = z*log2e
    return RCPF(1.0f + EXP2F(-s));
}
__device__ __forceinline__ float tanh2(float t) {   // t = 2*z*log2e
    return 1.0f - 2.0f * RCPF(1.0f + EXP2F(t));
}

// ---- weight prep: transpose to col-major [col][k], cast fp16, fold log2e ----
__global__ void prep_weights(const float* __restrict__ W1, const float* __restrict__ U1,
                             const float* __restrict__ b1, const float* __restrict__ W2,
                             const float* __restrict__ U2, const float* __restrict__ b2,
                             _Float16* __restrict__ Wp1, _Float16* __restrict__ Up1,
                             _Float16* __restrict__ Wp2, _Float16* __restrict__ Up2,
                             float* __restrict__ bp1, float* __restrict__ bp2) {
    int i = blockIdx.x * 256 + threadIdx.x;
    if (i < 32768) {                       // Wp1 [512][64] from W1 [64][512]
        int col = i >> 6, k = i & 63;
        float sc = ((col >> 7) == 2) ? TWOLOG2E : LOG2E;
        Wp1[i] = (_Float16)(W1[k * 512 + col] * sc);
    } else if (i < 32768 + 65536) {        // Up1 [512][128] from U1 [128][512]
        int j = i - 32768; int col = j >> 7, k = j & 127;
        float sc = ((col >> 7) == 2) ? TWOLOG2E : LOG2E;
        Up1[j] = (_Float16)(U1[k * 512 + col] * sc);
    } else if (i < 32768 + 131072) {       // Wp2 [512][128] from W2 [128][512]
        int j = i - 98304; int col = j >> 7, k = j & 127;
        float sc = ((col >> 7) == 2) ? TWOLOG2E : LOG2E;
        Wp2[j] = (_Float16)(W2[k * 512 + col] * sc);
    } else if (i < 32768 + 196608) {       // Up2 [512][128] from U2 [128][512]
        int j = i - 163840; int col = j >> 7, k = j & 127;
        float sc = ((col >> 7) == 2) ? TWOLOG2E : LOG2E;
        Up2[j] = (_Float16)(U2[k * 512 + col] * sc);
    } else if (i < 32768 + 196608 + 1024) {
        int j = i - 229376;
        if (j < 512) {
            float sc = ((j >> 7) == 2) ? TWOLOG2E : LOG2E;
            bp1[j] = b1[j] * sc;
        } else {
            int col = j - 512;
            float sc = ((col >> 7) == 2) ? TWOLOG2E : LOG2E;
            bp2[col] = b2[col] * sc;
        }
    }
}

// ---- LSTM layer kernel ----
// IS_A: input = x (f32 [B,T,F]), writes hs fp16 [T,B,U].
// !IS_A: input = hs (fp16 [T,B,U]), fused dense at end.
template <bool IS_A>
__global__ __launch_bounds__(512, 2) void lstm_layer(
    const float* __restrict__ xA, const _Float16* __restrict__ xB,
    const _Float16* __restrict__ Wp,   // [512][KX] col-major, scaled fp16
    const _Float16* __restrict__ Up,   // [512][128]
    const float* __restrict__ bp,      // [512] scaled
    _Float16* __restrict__ hs_out,
    const float* __restrict__ Wd, const float* __restrict__ bd,
    float* __restrict__ dout) {
    constexpr int KX  = IS_A ? 64 : 128;
    constexpr int KXS = KX / 32;
    constexpr int PX  = IS_A ? 72 : 136;  // halfs; rows 16B-aligned, <=2-way banks
    constexpr int PH  = 136;
    constexpr int H0  = 0;                // h buffers: 2 rows x PH, double
    constexpr int H1  = 2 * PH;
    constexpr int X0  = 4 * PH;           // x buffers: 2 rows x PX, double
    constexpr int X1  = X0 + 2 * PX;
    constexpr int SMH = X1 + 2 * PX;

    __shared__ __align__(16) _Float16 sm[SMH];

    const int tid  = threadIdx.x;
    const int lane = tid & 63;
    const int wv   = tid >> 6;       // 0..7, each owns 16 units x 4 gates
    const int m    = lane & 15;
    const int kc   = lane >> 4;      // quad 0..3
    const int u0   = wv * 16;
    const int b0   = blockIdx.x * 2;

    // zero LDS (h0 = 0 for t=0)
    for (int i = tid; i < SMH; i += 512) sm[i] = (_Float16)0.0f;

    // weight fragments -> registers (B-frag: B[k=kc*8+j][n=m], col-major source)
    h8 wf[4][KXS], uf[4][4];
#pragma unroll
    for (int g = 0; g < 4; g++) {
#pragma unroll
        for (int ks = 0; ks < KXS; ks++)
            wf[g][ks] = *(const h8*)&Wp[(g * 128 + u0 + m) * KX + ks * 32 + kc * 8];
#pragma unroll
        for (int ks = 0; ks < 4; ks++)
            uf[g][ks] = *(const h8*)&Up[(g * 128 + u0 + m) * 128 + ks * 32 + kc * 8];
    }
    float bias[4];
#pragma unroll
    for (int g = 0; g < 4; g++) bias[g] = bp[g * 128 + u0 + m];

    // PIN: clobber the weight pointers so reloads are unprovable -> the loaded
    // fragments must stay live in VGPRs across the whole time loop.
    asm volatile("" : "+s"(Wp), "+s"(Up), "+s"(bp) :: "memory");

    const bool stager = (wv == 4) && (lane >= 32);
    const int prow = (lane >> 4) - 2;   // 0..1 (stager lanes)
    const int pcol = lane & 15;

    __syncthreads();   // LDS zeroed

    // stage t=0 input into X0
    if (stager) {
        if constexpr (IS_A) {
            f4 v = *(const f4*)&xA[(size_t)((b0 + prow) * T_STEPS + 0) * FDIM + pcol * 4];
            h4 hv = {(_Float16)v.x, (_Float16)v.y, (_Float16)v.z, (_Float16)v.w};
            *(h4*)&sm[X0 + prow * PX + pcol * 4] = hv;
        } else {
            *(h8*)&sm[X0 + prow * PX + pcol * 8] =
                *(const h8*)&xB[(size_t)(0 * BATCH + b0 + prow) * NU + pcol * 8];
        }
    }
    __syncthreads();

    const h8 hzero = {(_Float16)0.f, (_Float16)0.f, (_Float16)0.f, (_Float16)0.f,
                      (_Float16)0.f, (_Float16)0.f, (_Float16)0.f, (_Float16)0.f};
    h8 xa[KXS], ha[4];
#pragma unroll
    for (int ks = 0; ks < KXS; ks++) xa[ks] = hzero;
#pragma unroll
    for (int ks = 0; ks < 4; ks++) ha[ks] = hzero;

    float c0 = 0.0f, c1 = 0.0f;

#pragma unroll 2
    for (int t = 0; t < T_STEPS; t++) {
        const int p = t & 1;

        // next-step global prefetch (consumed at end of step)
        f4 xr; h8 xr8;
        const bool pf = stager && (t + 1 < T_STEPS);
        if (pf) {
            if constexpr (IS_A)
                xr = *(const f4*)&xA[(size_t)((b0 + prow) * T_STEPS + (t + 1)) * FDIM + pcol * 4];
            else
                xr8 = *(const h8*)&xB[(size_t)((t + 1) * BATCH + b0 + prow) * NU + pcol * 8];
        }

        // A-frags: only rows 0,1 are real; lanes m>=2 keep stale/zero regs
        if (m < 2) {
            const _Float16* xb = &sm[p ? X1 : X0];
            const _Float16* hb = &sm[p ? H1 : H0];
#pragma unroll
            for (int ks = 0; ks < KXS; ks++)
                xa[ks] = *(const h8*)&xb[m * PX + ks * 32 + kc * 8];
#pragma unroll
            for (int ks = 0; ks < 4; ks++)
                ha[ks] = *(const h8*)&hb[m * PH + ks * 32 + kc * 8];
        }

        f4 acc[4];
#pragma unroll
        for (int g = 0; g < 4; g++)
            acc[g] = (f4){bias[g], bias[g], bias[g], bias[g]};
#pragma unroll
        for (int ks = 0; ks < KXS; ks++)
#pragma unroll
            for (int g = 0; g < 4; g++)
                acc[g] = __builtin_amdgcn_mfma_f32_16x16x32_f16(xa[ks], wf[g][ks], acc[g], 0, 0, 0);
#pragma unroll
        for (int ks = 0; ks < 4; ks++)
#pragma unroll
            for (int g = 0; g < 4; g++)
                acc[g] = __builtin_amdgcn_mfma_f32_16x16x32_f16(ha[ks], uf[g][ks], acc[g], 0, 0, 0);

        // in-wave epilogue: rows 0,1 live in regs 0,1 of lanes 0..15
        if (lane < 16) {
            float gi0 = sigm2(acc[0][0]), gf0 = sigm2(acc[1][0]);
            float gg0 = tanh2(acc[2][0]), go0 = sigm2(acc[3][0]);
            c0 = gf0 * c0 + gi0 * gg0;
            float hv0 = go0 * tanh2(c0 * TWOLOG2E);
            float gi1 = sigm2(acc[0][1]), gf1 = sigm2(acc[1][1]);
            float gg1 = tanh2(acc[2][1]), go1 = sigm2(acc[3][1]);
            c1 = gf1 * c1 + gi1 * gg1;
            float hv1 = go1 * tanh2(c1 * TWOLOG2E);
            _Float16 h0v = (_Float16)hv0, h1v = (_Float16)hv1;
            _Float16* hbn = &sm[p ? H0 : H1];
            hbn[u0 + m] = h0v;
            hbn[PH + u0 + m] = h1v;
            if constexpr (IS_A) {
                hs_out[((size_t)t * BATCH + b0    ) * NU + u0 + m] = h0v;
                hs_out[((size_t)t * BATCH + b0 + 1) * NU + u0 + m] = h1v;
            }
        }
        if (pf) {
            _Float16* xbn = &sm[p ? X0 : X1];
            if constexpr (IS_A) {
                h4 hv4 = {(_Float16)xr.x, (_Float16)xr.y, (_Float16)xr.z, (_Float16)xr.w};
                *(h4*)&xbn[prow * PX + pcol * 4] = hv4;
            } else {
                *(h8*)&xbn[prow * PX + pcol * 8] = xr8;
            }
        }
        __syncthreads();
    }

    if constexpr (!IS_A) {
        // h(T): t=255 (p=1) wrote into H0
        if (wv == 0) {
            int rw = lane >> 5, u = lane & 31;
            float s = 0.0f;
#pragma unroll
            for (int j = 0; j < 4; j++) {
                int uum = u + j * 32;
                s += (float)sm[H0 + rw * PH + uum] * Wd[uum];
            }
            s += __shfl_xor(s, 16);
            s += __shfl_xor(s, 8);
            s += __shfl_xor(s, 4);
            s += __shfl_xor(s, 2);
            s += __shfl_xor(s, 1);
            if ((lane & 31) == 0) dout[b0 + rw] = fmaxf(s + bd[0], 0.0f);
        }
    }
}

extern "C" void kernel_launch(void* const* d_in, const int* in_sizes, int n_in,
                              void* d_out, int out_size, void* d_ws, size_t ws_size,
                              hipStream_t stream) {
    const float* x  = (const float*)d_in[0];
    const float* W1 = (const float*)d_in[1];
    const float* U1 = (const float*)d_in[2];
    const float* b1 = (const float*)d_in[3];
    const float* W2 = (const float*)d_in[4];
    const float* U2 = (const float*)d_in[5];
    const float* b2 = (const float*)d_in[6];
    const float* Wd = (const float*)d_in[7];
    const float* bd = (const float*)d_in[8];
    float* out = (float*)d_out;

    const size_t HS   = 33554432;              // hs fp16 [256][512][128]
    const size_t oWp1 = HS;
    const size_t oUp1 = oWp1 + 65536;
    const size_t oWp2 = oUp1 + 131072;
    const size_t oUp2 = oWp2 + 131072;
    const size_t oBp1 = oUp2 + 131072;
    const size_t oBp2 = oBp1 + 2048;
    const size_t need = oBp2 + 2048;           // 34,017,280
    if (ws_size < need) return;

    char* ws = (char*)d_ws;
    _Float16* hs  = (_Float16*)ws;
    _Float16* Wp1 = (_Float16*)(ws + oWp1);
    _Float16* Up1 = (_Float16*)(ws + oUp1);
    _Float16* Wp2 = (_Float16*)(ws + oWp2);
    _Float16* Up2 = (_Float16*)(ws + oUp2);
    float*    bp1 = (float*)(ws + oBp1);
    float*    bp2 = (float*)(ws + oBp2);

    prep_weights<<<900, 256, 0, stream>>>(W1, U1, b1, W2, U2, b2,
                                          Wp1, Up1, Wp2, Up2, bp1, bp2);
    lstm_layer<true><<<256, 512, 0, stream>>>(x, nullptr, Wp1, Up1, bp1,
                                              hs, nullptr, nullptr, nullptr);
    lstm_layer<false><<<256, 512, 0, stream>>>(nullptr, hs, Wp2, Up2, bp2,
                                               nullptr, Wd, bd, out);
}